// Round 1
// baseline (429.741 us; speedup 1.0000x reference)
//
#include <hip/hip_runtime.h>

#define NTOT 65536   // B * NPG
#define DIM  512
#define BGR  64
#define NPG  1024
#define DROPN 512    // NPG - ceil(0.5 * NPG)

// ---- p[row] = dot(X[row,:], W) ; one wave (64 lanes) per row ----
__global__ void matvec_kernel(const float* __restrict__ X,
                              const float* __restrict__ W,
                              float* __restrict__ p) {
    int gid  = blockIdx.x * blockDim.x + threadIdx.x;
    int row  = gid >> 6;
    int lane = gid & 63;
    if (row >= NTOT) return;
    const float4* xr = (const float4*)(X + (size_t)row * DIM);
    const float4* wr = (const float4*)W;
    float4 a0 = xr[lane];
    float4 a1 = xr[lane + 64];
    float4 w0 = wr[lane];
    float4 w1 = wr[lane + 64];
    float s = a0.x*w0.x + a0.y*w0.y + a0.z*w0.z + a0.w*w0.w
            + a1.x*w1.x + a1.y*w1.y + a1.z*w1.z + a1.w*w1.w;
    #pragma unroll
    for (int off = 32; off > 0; off >>= 1)
        s += __shfl_down(s, off, 64);
    if (lane == 0) p[row] = s;
}

// ---- in-degree via float atomics (exact integer counts) ----
__global__ void deg_kernel(const int* __restrict__ dst,
                           float* __restrict__ deg, int E) {
    int e = blockIdx.x * blockDim.x + threadIdx.x;
    if (e < E) atomicAdd(&deg[dst[e]], 1.0f);
}

// ---- hn[i] = p[i] * deg[i]^-0.5 (0 if deg==0) ----
__global__ void hn_kernel(const float* __restrict__ p,
                          const float* __restrict__ deg,
                          float* __restrict__ hn) {
    int i = blockIdx.x * blockDim.x + threadIdx.x;
    if (i < NTOT) {
        float d = deg[i];
        float nrm = d > 0.f ? (1.0f / sqrtf(d)) : 0.f;
        hn[i] = p[i] * nrm;
    }
}

// ---- agg[dst] += hn[src] over edges ----
__global__ void agg_kernel(const int* __restrict__ src,
                           const int* __restrict__ dst,
                           const float* __restrict__ hn,
                           float* __restrict__ agg, int E) {
    int e = blockIdx.x * blockDim.x + threadIdx.x;
    if (e < E) atomicAdd(&agg[dst[e]], hn[src[e]]);
}

// ---- per-graph: scores w = relu(agg*norm + bias); stable-sort select;
//      gate[i] = 0 for the DROPN smallest (ties by index), else w[i] ----
__global__ void topk_kernel(const float* __restrict__ agg,
                            const float* __restrict__ deg,
                            const float* __restrict__ bias,
                            float* __restrict__ gate) {
    __shared__ unsigned long long keys[NPG];
    __shared__ float wv[NPG];
    int base = blockIdx.x * NPG;
    float b = bias[0];
    for (int i = threadIdx.x; i < NPG; i += blockDim.x) {
        float d = deg[base + i];
        float nrm = d > 0.f ? (1.0f / sqrtf(d)) : 0.f;
        float w = agg[base + i] * nrm + b;
        w = w > 0.f ? w : 0.f;          // relu; w >= 0 so float bits are order-preserving
        wv[i] = w;
        keys[i] = ((unsigned long long)__float_as_uint(w) << 32) | (unsigned int)i;
    }
    __syncthreads();
    // bitonic sort ascending on 1024 composite keys (value, index) == jnp stable argsort
    for (int k = 2; k <= NPG; k <<= 1) {
        for (int j = k >> 1; j > 0; j >>= 1) {
            for (int i = threadIdx.x; i < NPG; i += blockDim.x) {
                int ixj = i ^ j;
                if (ixj > i) {
                    unsigned long long a = keys[i], c = keys[ixj];
                    bool up = ((i & k) == 0);
                    if ((a > c) == up) { keys[i] = c; keys[ixj] = a; }
                }
            }
            __syncthreads();
        }
    }
    for (int s = threadIdx.x; s < NPG; s += blockDim.x) {
        int idx = (int)(keys[s] & 0xffffffffull);
        gate[base + idx] = (s < DROPN) ? 0.f : wv[idx];
    }
}

// ---- out[row,:] = X[row,:] * gate[row]; skip feature read for dropped rows ----
__global__ void gate_kernel(const float* __restrict__ X,
                            const float* __restrict__ gate,
                            float* __restrict__ out) {
    int gid  = blockIdx.x * blockDim.x + threadIdx.x;
    int row  = gid >> 6;
    int lane = gid & 63;
    if (row >= NTOT) return;
    float g = gate[row];
    float4* orow = (float4*)(out + (size_t)row * DIM);
    if (g == 0.f) {          // wave-uniform branch (whole wave = one row)
        float4 z = make_float4(0.f, 0.f, 0.f, 0.f);
        orow[lane] = z;
        orow[lane + 64] = z;
    } else {
        const float4* xr = (const float4*)(X + (size_t)row * DIM);
        float4 a = xr[lane], c = xr[lane + 64];
        a.x *= g; a.y *= g; a.z *= g; a.w *= g;
        c.x *= g; c.y *= g; c.z *= g; c.w *= g;
        orow[lane] = a;
        orow[lane + 64] = c;
    }
}

extern "C" void kernel_launch(void* const* d_in, const int* in_sizes, int n_in,
                              void* d_out, int out_size, void* d_ws, size_t ws_size,
                              hipStream_t stream) {
    const float* X    = (const float*)d_in[0];
    const int*   src  = (const int*)d_in[1];
    const int*   dst  = (const int*)d_in[2];
    const float* W    = (const float*)d_in[3];
    const float* bias = (const float*)d_in[4];
    float* out = (float*)d_out;
    int E = in_sizes[1];

    float* ws   = (float*)d_ws;
    float* p    = ws;              // [N]
    float* hn   = ws + 1 * NTOT;   // [N]
    float* deg  = ws + 2 * NTOT;   // [N] must be zeroed
    float* agg  = ws + 3 * NTOT;   // [N] must be zeroed
    float* gate = ws + 4 * NTOT;   // [N]

    hipMemsetAsync(deg, 0, 2 * NTOT * sizeof(float), stream);  // deg + agg

    matvec_kernel<<<NTOT / 4, 256, 0, stream>>>(X, W, p);
    deg_kernel<<<(E + 255) / 256, 256, 0, stream>>>(dst, deg, E);
    hn_kernel<<<NTOT / 256, 256, 0, stream>>>(p, deg, hn);
    agg_kernel<<<(E + 255) / 256, 256, 0, stream>>>(src, dst, hn, agg, E);
    topk_kernel<<<BGR, 256, 0, stream>>>(agg, deg, bias, gate);
    gate_kernel<<<NTOT / 4, 256, 0, stream>>>(X, gate, out);
}

// Round 2
// 339.423 us; speedup vs baseline: 1.2661x; 1.2661x over previous
//
#include <hip/hip_runtime.h>

#define NTOT 65536   // B * NPG
#define DIM  512
#define BGR  64
#define NPG  1024
#define DROPN 512    // NPG - ceil(0.5 * NPG)

// ---- p[row] = dot(X[row,:], W) ; one wave (64 lanes) per row ----
__global__ void matvec_kernel(const float* __restrict__ X,
                              const float* __restrict__ W,
                              float* __restrict__ p) {
    int gid  = blockIdx.x * blockDim.x + threadIdx.x;
    int row  = gid >> 6;
    int lane = gid & 63;
    if (row >= NTOT) return;
    const float4* xr = (const float4*)(X + (size_t)row * DIM);
    const float4* wr = (const float4*)W;
    float4 a0 = xr[lane];
    float4 a1 = xr[lane + 64];
    float4 w0 = wr[lane];
    float4 w1 = wr[lane + 64];
    float s = a0.x*w0.x + a0.y*w0.y + a0.z*w0.z + a0.w*w0.w
            + a1.x*w1.x + a1.y*w1.y + a1.z*w1.z + a1.w*w1.w;
    #pragma unroll
    for (int off = 32; off > 0; off >>= 1)
        s += __shfl_down(s, off, 64);
    if (lane == 0) p[row] = s;
}

// ---- fused per-graph: degree, norm, scatter-sum, score, top-k -> gate ----
// One 1024-thread block per graph. All edges of graph g live in
// [g*epg, (g+1)*epg) and reference only nodes [g*NPG, (g+1)*NPG) -> LDS-local.
__global__ __launch_bounds__(1024) void fused_graph_kernel(
        const int* __restrict__ src, const int* __restrict__ dst,
        const float* __restrict__ p, const float* __restrict__ bias,
        float* __restrict__ gate, int epg) {
    __shared__ float degs[NPG];
    __shared__ float hn[NPG];               // reused as wv after pass 2
    __shared__ float agg[NPG];
    __shared__ unsigned long long keys[NPG];

    const int g = blockIdx.x;
    const int t = threadIdx.x;
    const int nbase = g * NPG;

    degs[t] = 0.f;
    agg[t]  = 0.f;
    __syncthreads();

    // ---- pass 1: in-degree (LDS atomics; float adds of 1.0 are exact) ----
    const int4* dst4 = (const int4*)(dst + (size_t)g * epg);
    const int4* src4 = (const int4*)(src + (size_t)g * epg);
    const int n4 = epg >> 2;
    for (int i = t; i < n4; i += 1024) {
        int4 d = dst4[i];
        atomicAdd(&degs[d.x - nbase], 1.f);
        atomicAdd(&degs[d.y - nbase], 1.f);
        atomicAdd(&degs[d.z - nbase], 1.f);
        atomicAdd(&degs[d.w - nbase], 1.f);
    }
    __syncthreads();

    // ---- norm + projected/normalized score contribution ----
    const float d   = degs[t];
    const float nrm = d > 0.f ? (1.0f / sqrtf(d)) : 0.f;
    hn[t] = p[nbase + t] * nrm;
    __syncthreads();

    // ---- pass 2: agg[dst] += hn[src] ----
    for (int i = t; i < n4; i += 1024) {
        int4 s = src4[i];
        int4 d2 = dst4[i];
        atomicAdd(&agg[d2.x - nbase], hn[s.x - nbase]);
        atomicAdd(&agg[d2.y - nbase], hn[s.y - nbase]);
        atomicAdd(&agg[d2.z - nbase], hn[s.z - nbase]);
        atomicAdd(&agg[d2.w - nbase], hn[s.w - nbase]);
    }
    __syncthreads();

    // ---- score: w = relu(agg*norm + bias); composite key for stable sort ----
    float w = agg[t] * nrm + bias[0];
    w = w > 0.f ? w : 0.f;                  // w >= 0 -> float bits order-preserving
    hn[t] = w;                              // hn now holds wv
    keys[t] = ((unsigned long long)__float_as_uint(w) << 32) | (unsigned int)t;
    __syncthreads();

    // ---- bitonic sort ascending; (value,index) key == jnp stable argsort ----
    for (int k = 2; k <= NPG; k <<= 1) {
        for (int j = k >> 1; j > 0; j >>= 1) {
            int ixj = t ^ j;
            if (ixj > t) {
                unsigned long long a = keys[t], c = keys[ixj];
                bool up = ((t & k) == 0);
                if ((a > c) == up) { keys[t] = c; keys[ixj] = a; }
            }
            __syncthreads();
        }
    }

    // ---- emit gate: zero the DROPN smallest ----
    int idx = (int)(keys[t] & 0xffffffffull);
    gate[nbase + idx] = (t < DROPN) ? 0.f : hn[idx];
}

// ---- out[row,:] = X[row,:] * gate[row]; skip feature read for dropped rows ----
__global__ void gate_kernel(const float* __restrict__ X,
                            const float* __restrict__ gate,
                            float* __restrict__ out) {
    int gid  = blockIdx.x * blockDim.x + threadIdx.x;
    int row  = gid >> 6;
    int lane = gid & 63;
    if (row >= NTOT) return;
    float g = gate[row];
    float4* orow = (float4*)(out + (size_t)row * DIM);
    if (g == 0.f) {          // wave-uniform branch (whole wave = one row)
        float4 z = make_float4(0.f, 0.f, 0.f, 0.f);
        orow[lane] = z;
        orow[lane + 64] = z;
    } else {
        const float4* xr = (const float4*)(X + (size_t)row * DIM);
        float4 a = xr[lane], c = xr[lane + 64];
        a.x *= g; a.y *= g; a.z *= g; a.w *= g;
        c.x *= g; c.y *= g; c.z *= g; c.w *= g;
        orow[lane] = a;
        orow[lane + 64] = c;
    }
}

extern "C" void kernel_launch(void* const* d_in, const int* in_sizes, int n_in,
                              void* d_out, int out_size, void* d_ws, size_t ws_size,
                              hipStream_t stream) {
    const float* X    = (const float*)d_in[0];
    const int*   src  = (const int*)d_in[1];
    const int*   dst  = (const int*)d_in[2];
    const float* W    = (const float*)d_in[3];
    const float* bias = (const float*)d_in[4];
    float* out = (float*)d_out;
    int E   = in_sizes[1];
    int epg = E / BGR;

    float* ws   = (float*)d_ws;
    float* p    = ws;              // [N]
    float* gate = ws + NTOT;       // [N]

    matvec_kernel<<<NTOT / 4, 256, 0, stream>>>(X, W, p);
    fused_graph_kernel<<<BGR, 1024, 0, stream>>>(src, dst, p, bias, gate, epg);
    gate_kernel<<<NTOT / 4, 256, 0, stream>>>(X, gate, out);
}

// Round 3
// 284.873 us; speedup vs baseline: 1.5085x; 1.1915x over previous
//
#include <hip/hip_runtime.h>

#define NTOT 65536   // B * NPG
#define DIM  512
#define BGR  64
#define NPG  1024
#define DROPN 512    // NPG - ceil(0.5 * NPG)
#define SLICES 8     // edge slices per graph

typedef float vf4 __attribute__((ext_vector_type(4)));

// ---- p[row] = dot(X[row,:], W); wave-per-row, grid-stride, 2-row unroll ----
__global__ __launch_bounds__(256) void matvec_kernel(
        const float* __restrict__ X, const float* __restrict__ W,
        float* __restrict__ p) {
    const int lane = threadIdx.x & 63;
    const int nw   = (gridDim.x * blockDim.x) >> 6;              // total waves
    const int wid  = (blockIdx.x * blockDim.x + threadIdx.x) >> 6;
    const vf4* wr = (const vf4*)W;
    const vf4 w0 = wr[lane], w1 = wr[lane + 64];
    for (int row = wid; row < NTOT; row += 2 * nw) {
        const int row2 = row + nw;                               // NTOT % (2*nw) == 0
        const vf4* xr0 = (const vf4*)(X + (size_t)row  * DIM);
        const vf4* xr1 = (const vf4*)(X + (size_t)row2 * DIM);
        vf4 a0 = xr0[lane], a1 = xr0[lane + 64];
        vf4 b0 = xr1[lane], b1 = xr1[lane + 64];
        vf4 m0 = a0 * w0 + a1 * w1;
        vf4 m1 = b0 * w0 + b1 * w1;
        float s0 = m0[0] + m0[1] + m0[2] + m0[3];
        float s1 = m1[0] + m1[1] + m1[2] + m1[3];
        #pragma unroll
        for (int off = 32; off > 0; off >>= 1) {
            s0 += __shfl_down(s0, off, 64);
            s1 += __shfl_down(s1, off, 64);
        }
        if (lane == 0) { p[row] = s0; p[row2] = s1; }
    }
}

// ---- per-slice in-degree: LDS histogram, then global atomic merge ----
__global__ __launch_bounds__(256) void deg_partial_kernel(
        const int* __restrict__ dst, float* __restrict__ deg, int epg) {
    __shared__ int dl[NPG];
    const int g = blockIdx.x & (BGR - 1);
    const int slice = blockIdx.x >> 6;
    const int nbase = g * NPG;
    const int eps = epg / SLICES;
    for (int i = threadIdx.x; i < NPG; i += 256) dl[i] = 0;
    __syncthreads();
    const int4* d4 = (const int4*)(dst + (size_t)g * epg + (size_t)slice * eps);
    const int n4 = eps >> 2;
    for (int i = threadIdx.x; i < n4; i += 256) {
        int4 d = d4[i];
        atomicAdd(&dl[d.x - nbase], 1);
        atomicAdd(&dl[d.y - nbase], 1);
        atomicAdd(&dl[d.z - nbase], 1);
        atomicAdd(&dl[d.w - nbase], 1);
    }
    __syncthreads();
    for (int i = threadIdx.x; i < NPG; i += 256) {
        int c = dl[i];
        if (c) atomicAdd(&deg[nbase + i], (float)c);
    }
}

// ---- hn[i] = p[i] * deg[i]^-0.5 ----
__global__ __launch_bounds__(256) void hn_kernel(
        const float* __restrict__ p, const float* __restrict__ deg,
        float* __restrict__ hn) {
    int i = blockIdx.x * blockDim.x + threadIdx.x;
    if (i < NTOT) {
        float d = deg[i];
        float nrm = d > 0.f ? (1.0f / sqrtf(d)) : 0.f;
        hn[i] = p[i] * nrm;
    }
}

// ---- per-slice agg: stage hn slice in LDS, LDS-local scatter, global merge ----
__global__ __launch_bounds__(256) void agg_partial_kernel(
        const int* __restrict__ src, const int* __restrict__ dst,
        const float* __restrict__ hn, float* __restrict__ agg, int epg) {
    __shared__ float al[NPG];
    __shared__ float hl[NPG];
    const int g = blockIdx.x & (BGR - 1);
    const int slice = blockIdx.x >> 6;
    const int nbase = g * NPG;
    const int eps = epg / SLICES;
    for (int i = threadIdx.x; i < NPG; i += 256) {
        al[i] = 0.f;
        hl[i] = hn[nbase + i];
    }
    __syncthreads();
    const int4* s4 = (const int4*)(src + (size_t)g * epg + (size_t)slice * eps);
    const int4* d4 = (const int4*)(dst + (size_t)g * epg + (size_t)slice * eps);
    const int n4 = eps >> 2;
    for (int i = threadIdx.x; i < n4; i += 256) {
        int4 s = s4[i];
        int4 d = d4[i];
        atomicAdd(&al[d.x - nbase], hl[s.x - nbase]);
        atomicAdd(&al[d.y - nbase], hl[s.y - nbase]);
        atomicAdd(&al[d.z - nbase], hl[s.z - nbase]);
        atomicAdd(&al[d.w - nbase], hl[s.w - nbase]);
    }
    __syncthreads();
    for (int i = threadIdx.x; i < NPG; i += 256) {
        float v = al[i];
        if (v != 0.f) atomicAdd(&agg[nbase + i], v);   // adding exact 0 is a no-op
    }
}

// ---- per-graph: w = relu(agg*norm + bias); stable bitonic sort; emit gate ----
__global__ __launch_bounds__(1024) void topk_kernel(
        const float* __restrict__ agg, const float* __restrict__ deg,
        const float* __restrict__ bias, float* __restrict__ gate) {
    __shared__ unsigned long long keys[NPG];
    __shared__ float wv[NPG];
    const int g = blockIdx.x;
    const int t = threadIdx.x;
    const int nbase = g * NPG;
    float d = deg[nbase + t];
    float nrm = d > 0.f ? (1.0f / sqrtf(d)) : 0.f;
    float w = agg[nbase + t] * nrm + bias[0];
    w = w > 0.f ? w : 0.f;                  // w >= 0 -> float bits order-preserving
    wv[t] = w;
    keys[t] = ((unsigned long long)__float_as_uint(w) << 32) | (unsigned int)t;
    __syncthreads();
    for (int k = 2; k <= NPG; k <<= 1) {
        for (int j = k >> 1; j > 0; j >>= 1) {
            int ixj = t ^ j;
            if (ixj > t) {
                unsigned long long a = keys[t], c = keys[ixj];
                bool up = ((t & k) == 0);
                if ((a > c) == up) { keys[t] = c; keys[ixj] = a; }
            }
            __syncthreads();
        }
    }
    int idx = (int)(keys[t] & 0xffffffffull);
    gate[nbase + idx] = (t < DROPN) ? 0.f : wv[idx];
}

// ---- out[row,:] = X[row,:] * gate[row]; grid-stride wave-per-row ----
__global__ __launch_bounds__(256) void gate_kernel(
        const float* __restrict__ X, const float* __restrict__ gate,
        float* __restrict__ out) {
    const int lane = threadIdx.x & 63;
    const int nw   = (gridDim.x * blockDim.x) >> 6;
    const int wid  = (blockIdx.x * blockDim.x + threadIdx.x) >> 6;
    for (int row = wid; row < NTOT; row += nw) {
        float g = gate[__builtin_amdgcn_readfirstlane(row)];   // wave-uniform -> s_load
        vf4* o = (vf4*)(out + (size_t)row * DIM);
        if (g == 0.f) {                    // wave-uniform branch, skip X read
            vf4 z = (vf4){0.f, 0.f, 0.f, 0.f};
            __builtin_nontemporal_store(z, &o[lane]);
            __builtin_nontemporal_store(z, &o[lane + 64]);
        } else {
            const vf4* xr = (const vf4*)(X + (size_t)row * DIM);
            vf4 a = xr[lane] * g;
            vf4 c = xr[lane + 64] * g;
            __builtin_nontemporal_store(a, &o[lane]);
            __builtin_nontemporal_store(c, &o[lane + 64]);
        }
    }
}

extern "C" void kernel_launch(void* const* d_in, const int* in_sizes, int n_in,
                              void* d_out, int out_size, void* d_ws, size_t ws_size,
                              hipStream_t stream) {
    const float* X    = (const float*)d_in[0];
    const int*   src  = (const int*)d_in[1];
    const int*   dst  = (const int*)d_in[2];
    const float* W    = (const float*)d_in[3];
    const float* bias = (const float*)d_in[4];
    float* out = (float*)d_out;
    int E   = in_sizes[1];
    int epg = E / BGR;

    float* ws   = (float*)d_ws;
    float* p    = ws;              // [N]
    float* hn   = ws + 1 * NTOT;   // [N]
    float* deg  = ws + 2 * NTOT;   // [N] zeroed
    float* agg  = ws + 3 * NTOT;   // [N] zeroed
    float* gate = ws + 4 * NTOT;   // [N]

    hipMemsetAsync(deg, 0, 2 * NTOT * sizeof(float), stream);  // deg + agg

    matvec_kernel<<<2048, 256, 0, stream>>>(X, W, p);
    deg_partial_kernel<<<BGR * SLICES, 256, 0, stream>>>(dst, deg, epg);
    hn_kernel<<<NTOT / 256, 256, 0, stream>>>(p, deg, hn);
    agg_partial_kernel<<<BGR * SLICES, 256, 0, stream>>>(src, dst, hn, agg, epg);
    topk_kernel<<<BGR, 1024, 0, stream>>>(agg, deg, bias, gate);
    gate_kernel<<<2048, 256, 0, stream>>>(X, gate, out);
}

// Round 4
// 280.198 us; speedup vs baseline: 1.5337x; 1.0167x over previous
//
#include <hip/hip_runtime.h>

#define NTOT 65536   // B * NPG
#define DIM  512
#define BGR  64
#define NPG  1024
#define DROPN 512    // NPG - ceil(0.5 * NPG)
#define SLICES 8     // edge slices per graph
#define MV_BLOCKS 2048

typedef float vf4 __attribute__((ext_vector_type(4)));
typedef unsigned long long u64;

// ---- K1: blocks [0,2048): p = X@W (wave-per-row); blocks [2048,2560):
//      per-(graph,slice) in-degree partials via LDS histogram (no atomics in HBM)
__global__ __launch_bounds__(256) void k1_matvec_deg(
        const float* __restrict__ X, const float* __restrict__ W,
        const int* __restrict__ dst,
        float* __restrict__ p, int* __restrict__ deg_part, int epg) {
    __shared__ int dl[NPG];
    if (blockIdx.x < MV_BLOCKS) {
        const int lane = threadIdx.x & 63;
        const int wid  = (blockIdx.x * 256 + threadIdx.x) >> 6;   // 0..8191
        const int nw   = (MV_BLOCKS * 256) >> 6;                  // 8192 waves
        const vf4* wr = (const vf4*)W;
        const vf4 w0 = wr[lane], w1 = wr[lane + 64];
        for (int row = wid; row < NTOT; row += 2 * nw) {
            const int row2 = row + nw;
            const vf4* xr0 = (const vf4*)(X + (size_t)row  * DIM);
            const vf4* xr1 = (const vf4*)(X + (size_t)row2 * DIM);
            vf4 a0 = xr0[lane], a1 = xr0[lane + 64];
            vf4 b0 = xr1[lane], b1 = xr1[lane + 64];
            vf4 m0 = a0 * w0 + a1 * w1;
            vf4 m1 = b0 * w0 + b1 * w1;
            float s0 = m0[0] + m0[1] + m0[2] + m0[3];
            float s1 = m1[0] + m1[1] + m1[2] + m1[3];
            #pragma unroll
            for (int off = 32; off > 0; off >>= 1) {
                s0 += __shfl_down(s0, off, 64);
                s1 += __shfl_down(s1, off, 64);
            }
            if (lane == 0) { p[row] = s0; p[row2] = s1; }
        }
    } else {
        const int b = blockIdx.x - MV_BLOCKS;                     // 0..511
        const int g = b & (BGR - 1);
        const int slice = b >> 6;
        const int nbase = g * NPG;
        const int eps = epg / SLICES;
        for (int i = threadIdx.x; i < NPG; i += 256) dl[i] = 0;
        __syncthreads();
        const int4* d4 = (const int4*)(dst + (size_t)g * epg + (size_t)slice * eps);
        const int n4 = eps >> 2;
        for (int i = threadIdx.x; i < n4; i += 256) {
            int4 d = d4[i];
            atomicAdd(&dl[d.x - nbase], 1);
            atomicAdd(&dl[d.y - nbase], 1);
            atomicAdd(&dl[d.z - nbase], 1);
            atomicAdd(&dl[d.w - nbase], 1);
        }
        __syncthreads();
        int* out = deg_part + (size_t)slice * NTOT + nbase;
        for (int i = threadIdx.x; i < NPG; i += 256) out[i] = dl[i];
    }
}

// ---- K2: per (graph,slice): sum deg partials -> norm; hn staged in LDS;
//      LDS scatter-sum of slice edges; write agg partial (no global atomics)
__global__ __launch_bounds__(256) void k2_agg(
        const int* __restrict__ src, const int* __restrict__ dst,
        const float* __restrict__ p, const int* __restrict__ deg_part,
        float* __restrict__ agg_part, float* __restrict__ norm_out, int epg) {
    __shared__ float hl[NPG];
    __shared__ float al[NPG];
    const int b = blockIdx.x;
    const int g = b & (BGR - 1);
    const int slice = b >> 6;
    const int nbase = g * NPG;
    const int eps = epg / SLICES;
    for (int i = threadIdx.x; i < NPG; i += 256) {
        int d = 0;
        #pragma unroll
        for (int s = 0; s < SLICES; s++) d += deg_part[(size_t)s * NTOT + nbase + i];
        float nrm = d > 0 ? (1.0f / sqrtf((float)d)) : 0.f;
        hl[i] = p[nbase + i] * nrm;
        al[i] = 0.f;
        if (slice == 0) norm_out[nbase + i] = nrm;
    }
    __syncthreads();
    const int4* s4 = (const int4*)(src + (size_t)g * epg + (size_t)slice * eps);
    const int4* d4 = (const int4*)(dst + (size_t)g * epg + (size_t)slice * eps);
    const int n4 = eps >> 2;
    for (int i = threadIdx.x; i < n4; i += 256) {
        int4 s = s4[i];
        int4 d = d4[i];
        atomicAdd(&al[d.x - nbase], hl[s.x - nbase]);
        atomicAdd(&al[d.y - nbase], hl[s.y - nbase]);
        atomicAdd(&al[d.z - nbase], hl[s.z - nbase]);
        atomicAdd(&al[d.w - nbase], hl[s.w - nbase]);
    }
    __syncthreads();
    float* out = agg_part + (size_t)slice * NTOT + nbase;
    for (int i = threadIdx.x; i < NPG; i += 256) out[i] = al[i];
}

// ---- K3: per graph: w = relu(agg*norm + bias); hybrid register bitonic sort
//      (shfl_xor for j<=32, LDS only for j>=64); emit gate ----
__global__ __launch_bounds__(1024) void k3_topk(
        const float* __restrict__ agg_part, const float* __restrict__ norm,
        const float* __restrict__ bias, float* __restrict__ gate) {
    __shared__ u64 sk[NPG];
    const int g = blockIdx.x;
    const int t = threadIdx.x;
    const int nbase = g * NPG;
    float a = 0.f;
    #pragma unroll
    for (int s = 0; s < SLICES; s++) a += agg_part[(size_t)s * NTOT + nbase + t];
    float w = a * norm[nbase + t] + bias[0];
    w = w > 0.f ? w : 0.f;                // relu; w>=0 -> float bits order-preserving
    u64 key = ((u64)__float_as_uint(w) << 32) | (unsigned int)t;

    // ascending bitonic sort of 1024 unique composite keys == jnp stable argsort
    for (int k = 2; k <= NPG; k <<= 1) {
        const bool up = ((t & k) == 0);
        for (int j = k >> 1; j >= 64; j >>= 1) {      // cross-wave: LDS exchange
            sk[t] = key;
            __syncthreads();
            u64 partner = sk[t ^ j];
            __syncthreads();
            bool takeMin = (((t & j) == 0) == up);
            key = takeMin ? (key < partner ? key : partner)
                          : (key > partner ? key : partner);
        }
        for (int j = ((k >> 1) < 32 ? (k >> 1) : 32); j >= 1; j >>= 1) {  // in-wave
            u64 partner = (u64)__shfl_xor((long long)key, j, 64);
            bool takeMin = (((t & j) == 0) == up);
            key = takeMin ? (key < partner ? key : partner)
                          : (key > partner ? key : partner);
        }
    }
    int idx = (int)(key & 0xffffffffull);
    float wv = __uint_as_float((unsigned int)(key >> 32));
    gate[nbase + idx] = (t < DROPN) ? 0.f : wv;
}

// ---- K4: out[row,:] = X[row,:] * gate[row]; plain (L2) stores ----
__global__ __launch_bounds__(256) void k4_gate(
        const float* __restrict__ X, const float* __restrict__ gate,
        float* __restrict__ out) {
    const int lane = threadIdx.x & 63;
    const int nw   = (gridDim.x * blockDim.x) >> 6;
    const int wid  = (blockIdx.x * blockDim.x + threadIdx.x) >> 6;
    for (int row = wid; row < NTOT; row += nw) {
        float g = gate[row];
        vf4* o = (vf4*)(out + (size_t)row * DIM);
        if (g == 0.f) {                    // wave-uniform (whole wave = one row)
            vf4 z = (vf4){0.f, 0.f, 0.f, 0.f};
            o[lane] = z;
            o[lane + 64] = z;
        } else {
            const vf4* xr = (const vf4*)(X + (size_t)row * DIM);
            o[lane]      = xr[lane] * g;
            o[lane + 64] = xr[lane + 64] * g;
        }
    }
}

extern "C" void kernel_launch(void* const* d_in, const int* in_sizes, int n_in,
                              void* d_out, int out_size, void* d_ws, size_t ws_size,
                              hipStream_t stream) {
    const float* X    = (const float*)d_in[0];
    const int*   src  = (const int*)d_in[1];
    const int*   dst  = (const int*)d_in[2];
    const float* W    = (const float*)d_in[3];
    const float* bias = (const float*)d_in[4];
    float* out = (float*)d_out;
    int E   = in_sizes[1];
    int epg = E / BGR;

    float* ws       = (float*)d_ws;
    float* p        = ws;                       // [N] f32
    float* norm     = ws + 1 * NTOT;            // [N] f32
    float* gate     = ws + 2 * NTOT;            // [N] f32
    int*   deg_part = (int*)(ws + 3 * NTOT);    // [SLICES][N] i32
    float* agg_part = ws + (3 + SLICES) * NTOT; // [SLICES][N] f32

    k1_matvec_deg<<<MV_BLOCKS + BGR * SLICES, 256, 0, stream>>>(X, W, dst, p, deg_part, epg);
    k2_agg<<<BGR * SLICES, 256, 0, stream>>>(src, dst, p, deg_part, agg_part, norm, epg);
    k3_topk<<<BGR, 1024, 0, stream>>>(agg_part, norm, bias, gate);
    k4_gate<<<2048, 256, 0, stream>>>(X, gate, out);
}